// Round 10
// baseline (129.836 us; speedup 1.0000x reference)
//
#include <hip/hip_runtime.h>
#include <math.h>

// Problem constants
constexpr int Bn = 32;
constexpr int Cn = 512;
constexpr int Tn = 1024;
constexpr int KS = 13;

// Tiling (r18 chassis, verified 46.8us / absmax 0.0)
constexpr int CB   = 64;           // channels per block -> 256 blocks, 1 block/CU
constexpr int TT   = 64;           // timesteps per chunk
constexpr int NCH  = Tn / TT;      // 16 chunks
constexpr int DSTR = TT + 1;       // 65: scan bank (65c+j)%32=(c+j)%32 -> 2-way worst = free
constexpr int NCW  = 8;            // conv waves (SEG=8 keeps the VGPR-safe 20-float ring)
constexpr int SEG  = CB / NCW;     // 8 output rows per conv thread
constexpr int NL   = SEG + KS - 1; // 20 input rows per conv thread
constexpr int SRB  = 8;            // Sb ring depth (race-free by construction)

// ---------------------------------------------------------------------------
// r19 = r18 + BLOCK PHASE STAGGER (single change, decisive A/B).
// Post-mortems r8-r18: duration is invariant (~43-47us) under sync style,
// occupancy (1-3 waves/SIMD), period count, issue count (-30% instrs ->
// +8% dur!), and store granule width. The one invariant across ALL rounds:
// write throughput == 64MB/~45us ~= 1.4 TB/s, total HBM 2.1-2.6 TB/s.
// Theory: TEMPORAL CHANNEL IMBALANCE. All 256 blocks process the same
// t-chunk k at the same time (synchronized start + identical periods), and
// c/b address components are multiples of 4KB -- so each period, the entire
// chip's reads and writes fall in single 256B t-granules. If HBM channel
// interleave granularity is <=1KB, the chip hammers a few channels per
// period, rotating serially with k. Explains structure-independence AND
// r17's null result (wider granules, same t-granule).
// Fix: stagger block start by (bid&15) x ~450cyc (s_sleep(7) units) to
// spread block phases across ~one period -> ~16 concurrent t-granules
// chip-wide. Cost if wrong: ~2.8us tail.
// Falsifier: dur >= 44 && hbm <= 2.5 TB/s -> theory dead, pattern-roofline
// ~2.3-2.5 TB/s established, declare ROOFLINE.
// Everything else byte-identical to r18 (passed, absmax 0.0): 17-barrier
// schedule, conv ring, full-lane scan, Sb 8-ring, streaming stores.
// ---------------------------------------------------------------------------

__device__ __forceinline__ void wg_barrier() {
  asm volatile("" ::: "memory");
  __builtin_amdgcn_s_barrier();
  asm volatile("" ::: "memory");
}
__device__ __forceinline__ void lds_fence() {
  asm volatile("s_waitcnt lgkmcnt(0)" ::: "memory");
}

#define SCAN16(DV, TB)                                                   \
  _Pragma("unroll")                                                      \
  for (int j = 0; j < 16; ++j) {                                         \
    const float rthr = (mem > 0.5f) ? 0.5f : 0.0f;  /* reset: OLD mem */ \
    float a_  = __fmul_rn(0.95f, mem);                                   \
    float s2_ = __fadd_rn(a_, DV[j]);                                    \
    mem = __fsub_rn(s2_, rthr);                                          \
    const unsigned int bit = (mem > 0.5f) ? 1u : 0u;                     \
    if ((TB) + j < 32) lo |= bit << ((TB) + j);                          \
    else               hi |= bit << ((TB) + j - 32);                     \
  }

__global__ __launch_bounds__(640, 2)
void snn_fused(const float* __restrict__ x, const float* __restrict__ wp,
               float* __restrict__ out) {
  __shared__ float DA[CB][DSTR];             // drive double buffer (33.3 KB)
  __shared__ float DB[CB][DSTR];
  __shared__ __align__(8) uint2 Sb[SRB][CB + 1]; // spike ring (4.2 KB), +1 pad

  const int tid = threadIdx.x;
  const int b   = blockIdx.y;
  const int c0  = blockIdx.x * CB;
  const long xbase = (long)b * Cn * Tn;

  // ---- r19: phase stagger (block-uniform, before any memory traffic) ----
  {
    const int phase = (int)((blockIdx.y * gridDim.x + blockIdx.x) & 15u);
    for (int i = 0; i < phase; ++i) __builtin_amdgcn_s_sleep(7); // ~450cyc ea
  }

  // ---- Gaussian weights, numpy float32 bit-emulation (validated) ----
  float kw[KS];
  {
    float w  = wp[0];
    float wc = fminf(fmaxf(w, 1.0f), 10.0f);      // clip(w, 1, 10)
    float sigma = __fadd_rn(5.5f, wc);
    float e[KS];
#pragma unroll
    for (int i = 0; i < KS; ++i) {
      float q = __fdiv_rn((float)(i - 6), sigma);
      float t = __fmul_rn(-0.5f, __fmul_rn(q, q));
      e[i] = (float)exp((double)t);
    }
    // numpy pairwise_sum order for n=13
    float s = __fadd_rn(
        __fadd_rn(__fadd_rn(e[0], e[1]), __fadd_rn(e[2], e[3])),
        __fadd_rn(__fadd_rn(e[4], e[5]), __fadd_rn(e[6], e[7])));
    s = __fadd_rn(s, e[8]);  s = __fadd_rn(s, e[9]);  s = __fadd_rn(s, e[10]);
    s = __fadd_rn(s, e[11]); s = __fadd_rn(s, e[12]);
#pragma unroll
    for (int i = 0; i < KS; ++i) kw[i] = __fdiv_rn(e[i], s);
  }

  if (tid < 64) {
    // ============ scan wave: ALL 64 lanes active (lane = channel) ========
    const int c = tid;
    float mem = 0.0f;
    wg_barrier();                              // B0: D(0) published
    for (int k = 0; k < NCH; ++k) {
      const float* Dc = (k & 1) ? &DB[c][0] : &DA[c][0];
      unsigned int lo = 0u, hi = 0u;
      float dvA[16], dvB[16];                  // named arrays, const idx only
#pragma unroll
      for (int j = 0; j < 16; ++j) dvA[j] = Dc[j];
#pragma unroll
      for (int j = 0; j < 16; ++j) dvB[j] = Dc[16 + j];   // lookahead g=1
      SCAN16(dvA, 0)
#pragma unroll
      for (int j = 0; j < 16; ++j) dvA[j] = Dc[32 + j];   // lookahead g=2
      SCAN16(dvB, 16)
#pragma unroll
      for (int j = 0; j < 16; ++j) dvB[j] = Dc[48 + j];   // lookahead g=3
      SCAN16(dvA, 32)
      SCAN16(dvB, 48)
      Sb[k & (SRB - 1)][c] = make_uint2(lo, hi);
      lds_fence();                             // reads + Sb write retired
      wg_barrier();                            // B(k+1)
    }
  } else if (tid < 64 + 64 * NCW) {
    // ====== conv waves (register-ring producers, loads + LDS writes) ====
    const int ctid = tid - 64;
    const int col  = ctid & 63;                // t-column (lane)
    const int segS = (ctid >> 6) * SEG;        // 0,8,...,56
    const int cin0 = c0 + segS - 6;

    float xA[NL], xB[NL], xC[NL];              // 3-buffer rotation (named)

    auto load_chunk = [&](int m, float* dst) {
#pragma unroll
      for (int j = 0; j < NL; ++j) {
        const int gc = cin0 + j;
        float v = 0.0f;
        if (gc >= 0 && gc < Cn)                // zero pad; per-wave uniform
          v = x[xbase + (long)gc * Tn + m * TT + col];
        dst[j] = v;
      }
    };
    auto conv_chunk = [&](const float* xs, float (*D)[DSTR]) {
#pragma unroll
      for (int r = 0; r < SEG; ++r) {
        float acc = __fmul_rn(kw[0], xs[r]);   // ascending, no FMA
#pragma unroll
        for (int i = 1; i < KS; ++i)
          acc = __fadd_rn(acc, __fmul_rn(kw[i], xs[r + i]));
        D[segS + r][col] = __fsub_rn(xs[r + 6], acc);  // x - x_mean
      }
    };

    // prologue: fill ring, publish D(0)
    load_chunk(0, xA);
    load_chunk(1, xB);
    load_chunk(2, xC);
    conv_chunk(xA, DA);                        // chunk 0 -> DA (waits xA only)
    lds_fence();
    wg_barrier();                              // B0

    // STEPC(K): issue loads K+3 (distance-2), conv chunk K+1 from the buffer
    // loaded two iterations ago, lgkm, barrier. No vmcnt drain anywhere.
#define STEPC(K, BL, BC)                                                 \
    do {                                                                 \
      if ((K) + 3 < NCH) load_chunk((K) + 3, BL);                        \
      conv_chunk(BC, (((K) + 1) & 1) ? DB : DA);                         \
      lds_fence();                                                       \
      wg_barrier();                                                      \
    } while (0)

    for (int kb = 0; kb < NCH - 1; kb += 3) {  // kb=0,3,6,9,12 -> K=0..14
      STEPC(kb + 0, xA, xB);
      STEPC(kb + 1, xB, xC);
      STEPC(kb + 2, xC, xA);
    }
#undef STEPC
    wg_barrier();                              // B16 (iter 15: no conv work)
  } else {
    // ====== store wave (LDS broadcast reads + streaming dword stores) ===
    const int L = tid & 63;                    // t-column (lane)
    wg_barrier();                              // B0
    for (int k = 0; k < NCH; ++k) {
      wg_barrier();                            // B(k+1): Sb(k) published
      const uint2* Sp = Sb[k & (SRB - 1)];
      const long obase = xbase + (long)c0 * Tn + (long)k * TT + L;
#pragma unroll 8
      for (int r = 0; r < CB; ++r) {
        const uint2 wb = Sp[r];                // ds_read_b64 broadcast
        const unsigned ws = (L & 32) ? wb.y : wb.x;
        out[obase + (long)r * Tn] =
            ((ws >> (L & 31)) & 1u) ? 1.0f : 0.0f;       // fire & forget
      }
    }
  }
}

extern "C" void kernel_launch(void* const* d_in, const int* in_sizes, int n_in,
                              void* d_out, int out_size, void* d_ws, size_t ws_size,
                              hipStream_t stream) {
  const float* x  = (const float*)d_in[0];
  const float* w  = (const float*)d_in[1];
  float* out      = (float*)d_out;
  dim3 grid(Cn / CB, Bn, 1);                   // 8 x 32 = 256 blocks
  snn_fused<<<grid, 64 + 64 * NCW + 64, 0, stream>>>(x, w, out);
}